// Round 4
// baseline (399.250 us; speedup 1.0000x reference)
//
#include <hip/hip_runtime.h>

// B=8, NQ=1024, NC=4096, D=256, C+1=25. FP32 I/O; labels int32.
// All-fp16 MFMA pipeline (single term): error budget ~0.03-0.08 vs 0.216 thr.

typedef __attribute__((ext_vector_type(8))) _Float16 half8;
typedef __attribute__((ext_vector_type(4))) float floatx4;

#define WB 8
#define WNQ 1024
#define WNC 4096
#define NROWS 8192          // B*NQ

static __device__ __forceinline__ float logsig(float x) {
    return (x >= 0.f) ? -log1pf(__expf(-x)) : x - log1pf(__expf(x));
}

union V16h { int4 v; half8 h8; _Float16 h[8]; unsigned short s[8]; uint2 u2[2]; };
union F8   { float4 v[2]; float f[8]; };
union H4   { _Float16 h[4]; uint2 u; unsigned short s[4]; };

// ---------------------------------------------------------------------------
// wprep: WT fp16 [256 n][512 k] = W_rel^T; GenB fp16 [32 n][256 k]:
// n<25 -> Wgen[:,n], n==25 -> Wcp[0:256] (q-part of gate), else 0.
// ---------------------------------------------------------------------------
__global__ void wprep_kernel(const float* __restrict__ Wrel,
                             const float* __restrict__ Wgen,
                             const float* __restrict__ Wcp,
                             _Float16* __restrict__ WT,
                             _Float16* __restrict__ GenB)
{
    const int bx = blockIdx.x;
    if (bx < 256) {
        const int n = bx;
        for (int k = threadIdx.x; k < 512; k += 256)
            WT[(long)n * 512 + k] = (_Float16)Wrel[(long)k * 256 + n];
    } else {
        const int n = bx - 256;           // 0..31
        const int k = threadIdx.x;        // 0..255
        float v = 0.f;
        if (n < 25)      v = Wgen[(long)k * 25 + n];
        else if (n == 25) v = Wcp[k];
        GenB[(long)n * 256 + k] = (_Float16)v;
    }
}

// ---------------------------------------------------------------------------
// emb = concat(head,tail) @ W_rel + b_rel -> fp16. LDS-free, single-term.
// Blocks 0..127 q rows, 128..639 c rows. 4 waves; wave owns 64 n-cols.
// ---------------------------------------------------------------------------
__global__ __launch_bounds__(256, 4) void emb_kernel(
    const float* __restrict__ q_head, const float* __restrict__ q_tail,
    const float* __restrict__ c_head, const float* __restrict__ c_tail,
    const _Float16* __restrict__ WT,
    const float* __restrict__ brel,
    _Float16* __restrict__ Qf, _Float16* __restrict__ Cf)
{
    const int tid  = threadIdx.x;
    const int lane = tid & 63;
    const int wv   = tid >> 6;
    const int l15  = lane & 15;
    const int quad = lane >> 4;
    const int n0   = wv * 64;

    const float* head; const float* tail; _Float16* Ef; long m0;
    if (blockIdx.x < 128) {
        head = q_head; tail = q_tail; Ef = Qf; m0 = (long)blockIdx.x * 64;
    } else {
        head = c_head; tail = c_tail; Ef = Cf; m0 = (long)(blockIdx.x - 128) * 64;
    }

    floatx4 acc[4][4];
#pragma unroll
    for (int a = 0; a < 4; ++a)
#pragma unroll
        for (int bq = 0; bq < 4; ++bq) acc[a][bq] = (floatx4)(0.0f);

    for (int ks = 0; ks < 16; ++ks) {
        const int kg = ks * 32 + quad * 8;
        const float* srcb = (kg < 256) ? (head + kg) : (tail + (kg - 256));

        V16h bf[4];
#pragma unroll
        for (int nt = 0; nt < 4; ++nt)
            bf[nt].v = *(const int4*)(WT + (long)(n0 + nt * 16 + l15) * 512 + ks * 32 + quad * 8);

        V16h af[4];
#pragma unroll
        for (int mb = 0; mb < 4; ++mb) {
            const long row = m0 + mb * 16 + l15;
            F8 fv;
            fv.v[0] = *(const float4*)(srcb + row * 256);
            fv.v[1] = *(const float4*)(srcb + row * 256 + 4);
#pragma unroll
            for (int i = 0; i < 8; ++i) af[mb].h[i] = (_Float16)fv.f[i];
        }
#pragma unroll
        for (int mb = 0; mb < 4; ++mb)
#pragma unroll
            for (int nt = 0; nt < 4; ++nt)
                acc[mb][nt] = __builtin_amdgcn_mfma_f32_16x16x32_f16(af[mb].h8, bf[nt].h8, acc[mb][nt], 0, 0, 0);
    }

    float bias[4];
#pragma unroll
    for (int nt = 0; nt < 4; ++nt) bias[nt] = brel[n0 + nt * 16 + l15];
#pragma unroll
    for (int mb = 0; mb < 4; ++mb)
#pragma unroll
        for (int nt = 0; nt < 4; ++nt)
#pragma unroll
            for (int r = 0; r < 4; ++r) {
                const long row = m0 + mb * 16 + quad * 4 + r;
                Ef[row * 256 + n0 + nt * 16 + l15] = (_Float16)(acc[mb][nt][r] + bias[nt]);
            }
}

// ---------------------------------------------------------------------------
// gen head: genlog[8192][32] = q_emb @ [Wgen | Wcp_q] (+bgen). MFMA fp16.
// grid 128 blocks x 256; wave = 16 rows x 32 cols.
// ---------------------------------------------------------------------------
__global__ __launch_bounds__(256, 4) void gen_kernel(
    const _Float16* __restrict__ Qf,
    const _Float16* __restrict__ GenB,
    const float* __restrict__ bgen,
    float* __restrict__ genlog)
{
    const int tid  = threadIdx.x;
    const int lane = tid & 63;
    const int wv   = tid >> 6;
    const int l15  = lane & 15;
    const int quad = lane >> 4;
    const long m0  = (long)blockIdx.x * 64 + wv * 16;

    floatx4 acc[2];
    acc[0] = (floatx4)(0.0f); acc[1] = (floatx4)(0.0f);
#pragma unroll
    for (int ks = 0; ks < 8; ++ks) {
        V16h a, b0, b1;
        a.v  = *(const int4*)(Qf + (m0 + l15) * 256 + ks * 32 + quad * 8);
        b0.v = *(const int4*)(GenB + (long)(l15)      * 256 + ks * 32 + quad * 8);
        b1.v = *(const int4*)(GenB + (long)(16 + l15) * 256 + ks * 32 + quad * 8);
        acc[0] = __builtin_amdgcn_mfma_f32_16x16x32_f16(a.h8, b0.h8, acc[0], 0, 0, 0);
        acc[1] = __builtin_amdgcn_mfma_f32_16x16x32_f16(a.h8, b1.h8, acc[1], 0, 0, 0);
    }
#pragma unroll
    for (int nt = 0; nt < 2; ++nt) {
        const int col = nt * 16 + l15;
        const float bias = (col < 25) ? bgen[col] : 0.f;
#pragma unroll
        for (int r = 0; r < 4; ++r)
            genlog[(m0 + quad * 4 + r) * 32 + col] = acc[nt][r] + bias;
    }
}

// ---------------------------------------------------------------------------
// Fused flash attention + grouped class sums. 1D grid 16*8*ns, XCD-swizzled.
// LDS 41.4 KB -> 3 blocks/CU. XOR-swizzled unpadded cN; stride-36 swizzled cT.
// ---------------------------------------------------------------------------
__global__ __launch_bounds__(256, 3) void attn_kernel(
    const _Float16* __restrict__ qf,
    const _Float16* __restrict__ cf,
    const int*      __restrict__ labels,
    const float*    __restrict__ maskp,
    float* __restrict__ Opart,   // [ns*8192][288]
    float* __restrict__ Mst,
    float* __restrict__ Lst,
    int jtiles, int nsh)
{
    __shared__ _Float16 cN[32 * 256];   // natural [j][d], 16B-slot ^ (j&7)
    __shared__ _Float16 cT[288 * 36];   // transposed [d][j] + onehot rows 256..287
    __shared__ _Float16 Pw[4][16 * 40]; // per-wave P [q][j]
    __shared__ float mf[32];

    const int tid  = threadIdx.x;
    const int lane = tid & 63;
    const int wv   = tid >> 6;
    const int l15  = lane & 15;
    const int quad = lane >> 4;

    // XCD-aware decode: blocks sharing (b,sp) land on one XCD (id%8 heuristic)
    const int f   = blockIdx.x;
    const int xcd = f & 7;
    const int seq = f >> 3;
    const int qt  = seq & 15;
    const int u   = seq >> 4;
    const int pr  = u * 8 + xcd;
    const int b   = pr >> nsh;
    const int sp  = pr & ((1 << nsh) - 1);
    const int q0  = qt * 64;

    V16h qfr[8];
    {
        const long qrow = (long)b * WNQ + q0 + wv * 16 + l15;
#pragma unroll
        for (int ks = 0; ks < 8; ++ks)
            qfr[ks].v = *(const int4*)(qf + qrow * 256 + ks * 32 + quad * 8);
    }

    floatx4 O[18];
#pragma unroll
    for (int i = 0; i < 18; ++i) O[i] = (floatx4)(0.0f);
    float m_run = -INFINITY, l_run = 0.f;

    const int dg  = tid & 31;     // 16B d-slot (also class idx)
    const int jq  = tid >> 5;     // 0..7 j-group of 4
    const int j0s = jq * 4;
    const int sxr = l15 & 7;      // cN read swizzle

    for (int it = 0; it < jtiles; ++it) {
        const int jb = sp * (jtiles * 32) + it * 32;
        __syncthreads();
        {   // ---- stage c tile ----
            const long cbase = ((long)b * WNC + jb) * 256;
            V16h h0, h1, h2, h3;
            h0.v = *(const int4*)(cf + cbase + (j0s + 0) * 256 + dg * 8);
            h1.v = *(const int4*)(cf + cbase + (j0s + 1) * 256 + dg * 8);
            h2.v = *(const int4*)(cf + cbase + (j0s + 2) * 256 + dg * 8);
            h3.v = *(const int4*)(cf + cbase + (j0s + 3) * 256 + dg * 8);
            // natural, swizzled 16B slots
            *(int4*)&cN[(j0s + 0) * 256 + ((dg ^ ((j0s + 0) & 7)) << 3)] = h0.v;
            *(int4*)&cN[(j0s + 1) * 256 + ((dg ^ ((j0s + 1) & 7)) << 3)] = h1.v;
            *(int4*)&cN[(j0s + 2) * 256 + ((dg ^ ((j0s + 2) & 7)) << 3)] = h2.v;
            *(int4*)&cN[(j0s + 3) * 256 + ((dg ^ ((j0s + 3) & 7)) << 3)] = h3.v;
            // transposed: row d=dg*8+i, 8B slot jq ^ i ^ (dg&7)
#pragma unroll
            for (int i = 0; i < 8; ++i) {
                uint2 p;
                p.x = (unsigned int)h0.s[i] | ((unsigned int)h1.s[i] << 16);
                p.y = (unsigned int)h2.s[i] | ((unsigned int)h3.s[i] << 16);
                *(uint2*)&cT[(dg * 8 + i) * 36 + ((jq ^ i ^ (dg & 7)) << 2)] = p;
            }
            // onehot rows 256+cls
            const int4 lb = *(const int4*)(labels + (long)b * WNC + jb + j0s);
            const int* lbp = (const int*)&lb;
            H4 oh;
#pragma unroll
            for (int r = 0; r < 4; ++r) oh.s[r] = (lbp[r] == dg) ? 0x3C00u : 0u;
            *(uint2*)&cT[(256 + dg) * 36 + ((jq ^ (dg & 7) ^ (dg >> 3)) << 2)] = oh.u;
            if (tid < 8)
                *(float4*)&mf[tid * 4] = *(const float4*)(maskp + (long)b * WNC + jb + tid * 4);
        }
        __syncthreads();

        // ---- S^T = c (A, natural LDS) . q^T (B, regs) ----
        floatx4 accS[2];
        accS[0] = (floatx4)(0.0f); accS[1] = (floatx4)(0.0f);
#pragma unroll
        for (int ks = 0; ks < 8; ++ks) {
            const int slot = ((ks * 4 + quad) ^ sxr) << 3;
            V16h a0, a1;
            a0.v = *(const int4*)&cN[(l15)      * 256 + slot];
            a1.v = *(const int4*)&cN[(16 + l15) * 256 + slot];
            accS[0] = __builtin_amdgcn_mfma_f32_16x16x32_f16(a0.h8, qfr[ks].h8, accS[0], 0, 0, 0);
            accS[1] = __builtin_amdgcn_mfma_f32_16x16x32_f16(a1.h8, qfr[ks].h8, accS[1], 0, 0, 0);
        }
#pragma unroll
        for (int jf = 0; jf < 2; ++jf)
#pragma unroll
            for (int r = 0; r < 4; ++r) accS[jf][r] *= mf[jf * 16 + quad * 4 + r];

        // ---- online softmax per q = lane&15 ----
        float v = fmaxf(fmaxf(fmaxf(accS[0][0], accS[0][1]), fmaxf(accS[0][2], accS[0][3])),
                        fmaxf(fmaxf(accS[1][0], accS[1][1]), fmaxf(accS[1][2], accS[1][3])));
        v = fmaxf(v, __shfl_xor(v, 16, 64));
        v = fmaxf(v, __shfl_xor(v, 32, 64));
        const float m_new = fmaxf(m_run, v);
        const float alpha = __expf(m_run - m_new);
        float p[8]; float ts = 0.f;
#pragma unroll
        for (int jf = 0; jf < 2; ++jf)
#pragma unroll
            for (int r = 0; r < 4; ++r) {
                const float e = __expf(accS[jf][r] - m_new);
                p[jf * 4 + r] = e; ts += e;
            }
        ts += __shfl_xor(ts, 16, 64);
        ts += __shfl_xor(ts, 32, 64);
        l_run = l_run * alpha + ts;
        m_run = m_new;

        float ar[4];
#pragma unroll
        for (int r = 0; r < 4; ++r) ar[r] = __shfl(alpha, quad * 4 + r, 64);
#pragma unroll
        for (int fo = 0; fo < 18; ++fo)
#pragma unroll
            for (int r = 0; r < 4; ++r) O[fo][r] *= ar[r];

        // ---- P -> per-wave LDS (A layout [q][j]) ----
#pragma unroll
        for (int jf = 0; jf < 2; ++jf) {
            H4 w;
#pragma unroll
            for (int r = 0; r < 4; ++r) w.h[r] = (_Float16)p[jf * 4 + r];
            *(uint2*)&Pw[wv][l15 * 40 + jf * 16 + quad * 4] = w.u;
        }
        asm volatile("" ::: "memory");

        // ---- O += P @ [c | onehot] ----
        V16h pf;
        pf.v = *(const int4*)&Pw[wv][l15 * 40 + quad * 8];
#pragma unroll
        for (int dt = 0; dt < 18; ++dt) {
            const int base = (dt * 16 + l15) * 36;
            const int h    = (l15 & 7) ^ ((2 * dt + (l15 >> 3)) & 7);
            V16h bfr;
            bfr.u2[0] = *(const uint2*)&cT[base + (((2 * quad)     ^ h) << 2)];
            bfr.u2[1] = *(const uint2*)&cT[base + (((2 * quad + 1) ^ h) << 2)];
            O[dt] = __builtin_amdgcn_mfma_f32_16x16x32_f16(pf.h8, bfr.h8, O[dt], 0, 0, 0);
        }
    }

    {   // ---- store unnormalized partials + stats ----
        const long orow0 = (long)(sp * WB + b) * WNQ + q0 + wv * 16;
#pragma unroll
        for (int dt = 0; dt < 18; ++dt)
#pragma unroll
            for (int r = 0; r < 4; ++r)
                Opart[(orow0 + quad * 4 + r) * 288 + dt * 16 + l15] = O[dt][r];
        if (lane < 16) {
            const long sidx = (long)(sp * WB + b) * WNQ + q0 + wv * 16 + lane;
            Mst[sidx] = m_run;
            Lst[sidx] = l_run;
        }
    }
}

// ---------------------------------------------------------------------------
// Combine splits + log_softmax(gen) + gate + logaddexp. One wave per row.
// ---------------------------------------------------------------------------
__global__ __launch_bounds__(64) void final_kernel(
    const float* __restrict__ genlog,
    const float* __restrict__ Opart,
    const float* __restrict__ Mst,
    const float* __restrict__ Lst,
    const float* __restrict__ Wcp,
    const float* __restrict__ bcp,
    float* __restrict__ outp,
    int ns)
{
    __shared__ float gArr[32];
    __shared__ float cdArr[32];

    const int row  = blockIdx.x;
    const int lane = threadIdx.x;

    float ms[4];
#pragma unroll
    for (int s = 0; s < 4; ++s) ms[s] = (s < ns) ? Mst[(long)s * NROWS + row] : -INFINITY;
    const float mstar = fmaxf(fmaxf(ms[0], ms[1]), fmaxf(ms[2], ms[3]));
    float wgt[4]; float L = 0.f;
#pragma unroll
    for (int s = 0; s < 4; ++s) {
        wgt[s] = (ms[s] == -INFINITY) ? 0.f : __expf(ms[s] - mstar);
        if (s < ns) L += Lst[(long)s * NROWS + row] * wgt[s];
    }

    const int d0 = lane * 4;
    float ctx[4] = {0.f, 0.f, 0.f, 0.f};
#pragma unroll
    for (int s = 0; s < 4; ++s) {
        if (s < ns) {
            const float4 o = *(const float4*)&Opart[((long)s * NROWS + row) * 288 + d0];
            ctx[0] += wgt[s] * o.x; ctx[1] += wgt[s] * o.y;
            ctx[2] += wgt[s] * o.z; ctx[3] += wgt[s] * o.w;
        }
    }

    float cls[4] = {0.f, 0.f, 0.f, 0.f};
    if (lane < 8) {
#pragma unroll
        for (int s = 0; s < 4; ++s) {
            if (s < ns) {
                const float4 o = *(const float4*)&Opart[((long)s * NROWS + row) * 288 + 256 + lane * 4];
                cls[0] += wgt[s] * o.x; cls[1] += wgt[s] * o.y;
                cls[2] += wgt[s] * o.z; cls[3] += wgt[s] * o.w;
            }
        }
    }

    // gen log-softmax (logits precomputed)
    float g = (lane < 25) ? genlog[(long)row * 32 + lane] : -INFINITY;
    float mg = g;
#pragma unroll
    for (int off = 32; off >= 1; off >>= 1) mg = fmaxf(mg, __shfl_xor(mg, off, 64));
    float se = (lane < 25) ? __expf(g - mg) : 0.f;
#pragma unroll
    for (int off = 32; off >= 1; off >>= 1) se += __shfl_xor(se, off, 64);
    const float glsm = g - mg - logf(se);

    // gate: precomputed q-part (col 25) + ctx-part
    const float qgate = genlog[(long)row * 32 + 25];
    const float invL = 1.f / L;
    float part = 0.f;
#pragma unroll
    for (int i = 0; i < 4; ++i)
        part += ctx[i] * invL * Wcp[256 + d0 + i];
#pragma unroll
    for (int off = 32; off >= 1; off >>= 1) part += __shfl_xor(part, off, 64);
    const float logit = qgate + part + bcp[0];

    const float lscp  = logsig(logit);
    const float lsgen = logsig(-logit);
    const float logL  = logf(L);

    if (lane < 8) {
#pragma unroll
        for (int i = 0; i < 4; ++i)
            cdArr[lane * 4 + i] = (cls[i] > 0.f) ? (logf(cls[i]) - logL) : -INFINITY;
    }
    if (lane < 25) gArr[lane] = glsm;
    __syncthreads();

    if (lane < 25) {
        const float a  = lscp + cdArr[lane];
        const float bb = lsgen + gArr[lane];
        const float mx = fmaxf(a, bb);
        const float o  = (mx == -INFINITY) ? -INFINITY
                         : mx + log1pf(__expf(fminf(a, bb) - mx));
        outp[(long)row * 25 + lane] = o;
    }
}

// ---------------------------------------------------------------------------
extern "C" void kernel_launch(void* const* d_in, const int* in_sizes, int n_in,
                              void* d_out, int out_size, void* d_ws, size_t ws_size,
                              hipStream_t stream) {
    const float* q_head = (const float*)d_in[0];
    const float* q_tail = (const float*)d_in[1];
    const float* c_head = (const float*)d_in[2];
    const float* c_tail = (const float*)d_in[3];
    const int*   labels = (const int*)d_in[4];
    const float* maskp  = (const float*)d_in[5];
    const float* Wrel   = (const float*)d_in[6];
    const float* brel   = (const float*)d_in[7];
    const float* Wgen   = (const float*)d_in[8];
    const float* bgen   = (const float*)d_in[9];
    const float* Wcp    = (const float*)d_in[10];
    const float* bcp    = (const float*)d_in[11];

    auto need = [](long ns) -> long {
        return 22298624l + ns * (9437184l + 65536l);
    };
    int ns = 4, nsh = 2;
    if ((long)ws_size < need(4)) { ns = 2; nsh = 1; }
    if ((long)ws_size < need(2)) { ns = 1; nsh = 0; }
    const int jtiles = 128 / ns;

    char* ws = (char*)d_ws;
    _Float16* Qf    = (_Float16*)(ws);                    //  4 MB
    _Float16* Cf    = (_Float16*)(ws + 4194304l);         // 16 MB
    _Float16* WT    = (_Float16*)(ws + 20971520l);        // 256 KB
    _Float16* GenB  = (_Float16*)(ws + 21233664l);        // 16 KB
    float*    genlog= (float*)   (ws + 21250048l);        //  1 MB
    float*    Opart = (float*)   (ws + 22298624l);        // ns*9 MB
    float*    Mst   = (float*)   (ws + 22298624l + (long)ns * 9437184l);
    float*    Lst   = Mst + (long)ns * NROWS;

    hipLaunchKernelGGL(wprep_kernel, dim3(288), dim3(256), 0, stream,
                       Wrel, Wgen, Wcp, WT, GenB);
    hipLaunchKernelGGL(emb_kernel, dim3(640), dim3(256), 0, stream,
                       q_head, q_tail, c_head, c_tail, WT, brel, Qf, Cf);
    hipLaunchKernelGGL(gen_kernel, dim3(128), dim3(256), 0, stream,
                       Qf, GenB, bgen, genlog);
    hipLaunchKernelGGL(attn_kernel, dim3(16 * 8 * ns), dim3(256), 0, stream,
                       Qf, Cf, labels, maskp, Opart, Mst, Lst, jtiles, nsh);
    hipLaunchKernelGGL(final_kernel, dim3(NROWS), dim3(64), 0, stream,
                       genlog, Opart, Mst, Lst, Wcp, bcp, (float*)d_out, ns);
}

// Round 5
// 361.788 us; speedup vs baseline: 1.1035x; 1.1035x over previous
//
#include <hip/hip_runtime.h>

// B=8, NQ=1024, NC=4096, D=256, C+1=25. FP32 I/O; labels int32.
// All-fp16 MFMA pipeline. attn: global_load_lds staging of natural (sA) and
// pre-transposed (sB) c tiles into conflict-free interleaved LDS layouts.

typedef __attribute__((ext_vector_type(8))) _Float16 half8;
typedef __attribute__((ext_vector_type(4))) float floatx4;

#define WB 8
#define WNQ 1024
#define WNC 4096
#define NROWS 8192          // B*NQ

static __device__ __forceinline__ float logsig(float x) {
    return (x >= 0.f) ? -log1pf(__expf(-x)) : x - log1pf(__expf(x));
}

union V16h { int4 v; half8 h8; _Float16 h[8]; unsigned short s[8]; uint2 u2[2]; };
union F8   { float4 v[2]; float f[8]; };
union H4   { _Float16 h[4]; uint2 u; unsigned short s[4]; };

static __device__ __forceinline__ void async_lds16(const _Float16* g, _Float16* l) {
    __builtin_amdgcn_global_load_lds(
        (const __attribute__((address_space(1))) unsigned int*)g,
        (__attribute__((address_space(3))) unsigned int*)l,
        16, 0, 0);
}

// ---------------------------------------------------------------------------
// wprep: WT fp16 [256 n][512 k] = W_rel^T; GenB fp16 [32 n][256 k].
// ---------------------------------------------------------------------------
__global__ void wprep_kernel(const float* __restrict__ Wrel,
                             const float* __restrict__ Wgen,
                             const float* __restrict__ Wcp,
                             _Float16* __restrict__ WT,
                             _Float16* __restrict__ GenB)
{
    const int bx = blockIdx.x;
    if (bx < 256) {
        const int n = bx;
        for (int k = threadIdx.x; k < 512; k += 256)
            WT[(long)n * 512 + k] = (_Float16)Wrel[(long)k * 256 + n];
    } else {
        const int n = bx - 256;
        const int k = threadIdx.x;
        float v = 0.f;
        if (n < 25)       v = Wgen[(long)k * 25 + n];
        else if (n == 25) v = Wcp[k];
        GenB[(long)n * 256 + k] = (_Float16)v;
    }
}

// ---------------------------------------------------------------------------
// emb: concat(head,tail) @ W_rel + b_rel -> fp16 natural (+ transposed CfT
// for c rows). Block = 128m x 128n, 4 waves in 2x2 (halves load redundancy).
// Blocks 0..127 q, 128..639 c.
// ---------------------------------------------------------------------------
__global__ __launch_bounds__(256, 2) void emb_kernel(
    const float* __restrict__ q_head, const float* __restrict__ q_tail,
    const float* __restrict__ c_head, const float* __restrict__ c_tail,
    const _Float16* __restrict__ WT,
    const float* __restrict__ brel,
    _Float16* __restrict__ Qf, _Float16* __restrict__ Cf,
    _Float16* __restrict__ CfT)
{
    const int tid  = threadIdx.x;
    const int lane = tid & 63;
    const int wv   = tid >> 6;
    const int l15  = lane & 15;
    const int quad = lane >> 4;
    const int mi   = wv & 1;
    const int ni   = wv >> 1;

    const float* head; const float* tail; _Float16* Ef;
    long mbase; bool isQ;
    if (blockIdx.x < 128) {
        isQ = true;  head = q_head; tail = q_tail; Ef = Qf;
        mbase = (long)(blockIdx.x >> 1) * 128;
    } else {
        isQ = false; head = c_head; tail = c_tail; Ef = Cf;
        mbase = (long)((blockIdx.x - 128) >> 1) * 128;
    }
    const int nh = blockIdx.x & 1;
    const long m0 = mbase + mi * 64;
    const int  n0 = nh * 128 + ni * 64;

    floatx4 acc[4][4];
#pragma unroll
    for (int a = 0; a < 4; ++a)
#pragma unroll
        for (int bq = 0; bq < 4; ++bq) acc[a][bq] = (floatx4)(0.0f);

    for (int ks = 0; ks < 16; ++ks) {
        const int kg = ks * 32 + quad * 8;
        const float* srcb = (kg < 256) ? (head + kg) : (tail + (kg - 256));

        V16h bf[4];
#pragma unroll
        for (int nt = 0; nt < 4; ++nt)
            bf[nt].v = *(const int4*)(WT + (long)(n0 + nt * 16 + l15) * 512 + ks * 32 + quad * 8);

        V16h af[4];
#pragma unroll
        for (int mb = 0; mb < 4; ++mb) {
            const long row = m0 + mb * 16 + l15;
            F8 fv;
            fv.v[0] = *(const float4*)(srcb + row * 256);
            fv.v[1] = *(const float4*)(srcb + row * 256 + 4);
#pragma unroll
            for (int i = 0; i < 8; ++i) af[mb].h[i] = (_Float16)fv.f[i];
        }
#pragma unroll
        for (int mb = 0; mb < 4; ++mb)
#pragma unroll
            for (int nt = 0; nt < 4; ++nt)
                acc[mb][nt] = __builtin_amdgcn_mfma_f32_16x16x32_f16(af[mb].h8, bf[nt].h8, acc[mb][nt], 0, 0, 0);
    }

    float bias[4];
#pragma unroll
    for (int nt = 0; nt < 4; ++nt) bias[nt] = brel[n0 + nt * 16 + l15];

    const int bidx   = (int)(m0 >> 12);            // c batch (tile never crosses)
    const int jc0    = (int)(m0 & 4095);
#pragma unroll
    for (int mb = 0; mb < 4; ++mb)
#pragma unroll
        for (int nt = 0; nt < 4; ++nt)
#pragma unroll
            for (int r = 0; r < 4; ++r) {
                const long row = m0 + mb * 16 + quad * 4 + r;
                const _Float16 h = (_Float16)(acc[mb][nt][r] + bias[nt]);
                Ef[row * 256 + n0 + nt * 16 + l15] = h;
                if (!isQ) {
                    const int jc = jc0 + mb * 16 + quad * 4 + r;
                    CfT[(long)bidx * 1048576 + (long)(n0 + nt * 16 + l15) * 4096 + jc] = h;
                }
            }
}

// ---------------------------------------------------------------------------
// gen head: genlog[8192][32] = q_emb @ [Wgen | Wcp_q] (+bgen).
// ---------------------------------------------------------------------------
__global__ __launch_bounds__(256, 4) void gen_kernel(
    const _Float16* __restrict__ Qf,
    const _Float16* __restrict__ GenB,
    const float* __restrict__ bgen,
    float* __restrict__ genlog)
{
    const int tid  = threadIdx.x;
    const int lane = tid & 63;
    const int wv   = tid >> 6;
    const int l15  = lane & 15;
    const int quad = lane >> 4;
    const long m0  = (long)blockIdx.x * 64 + wv * 16;

    floatx4 acc[2];
    acc[0] = (floatx4)(0.0f); acc[1] = (floatx4)(0.0f);
#pragma unroll
    for (int ks = 0; ks < 8; ++ks) {
        V16h a, b0, b1;
        a.v  = *(const int4*)(Qf + (m0 + l15) * 256 + ks * 32 + quad * 8);
        b0.v = *(const int4*)(GenB + (long)(l15)      * 256 + ks * 32 + quad * 8);
        b1.v = *(const int4*)(GenB + (long)(16 + l15) * 256 + ks * 32 + quad * 8);
        acc[0] = __builtin_amdgcn_mfma_f32_16x16x32_f16(a.h8, b0.h8, acc[0], 0, 0, 0);
        acc[1] = __builtin_amdgcn_mfma_f32_16x16x32_f16(a.h8, b1.h8, acc[1], 0, 0, 0);
    }
#pragma unroll
    for (int nt = 0; nt < 2; ++nt) {
        const int col = nt * 16 + l15;
        const float bias = (col < 25) ? bgen[col] : 0.f;
#pragma unroll
        for (int r = 0; r < 4; ++r)
            genlog[(m0 + quad * 4 + r) * 32 + col] = acc[nt][r] + bias;
    }
}

// ---------------------------------------------------------------------------
// Fused flash attention + grouped class sums. grid 16qt*8b*ns (XCD swizzle).
// sA: natural c tile, unit u=(ks*2+jh)*64+quad*16+l15 (reads bank=4*(l15&7),
// conflict-free). sB: transposed tile, unit u=d*4+quad (reads bank=
// 16(l15&1)+4quad, conflict-free). Both staged via global_load_lds (16B).
// ---------------------------------------------------------------------------
__global__ __launch_bounds__(256, 3) void attn_kernel(
    const _Float16* __restrict__ qf,
    const _Float16* __restrict__ cf,
    const _Float16* __restrict__ cfT,
    const int*      __restrict__ labels,
    const float*    __restrict__ maskp,
    unsigned short* __restrict__ Oh,    // fp16 [ns*8192][288]
    float* __restrict__ Mst,
    float* __restrict__ Lst,
    int jtiles, int nsh)
{
    __shared__ _Float16 sA[8192];       // 16 KB
    __shared__ _Float16 sB[8192];       // 16 KB
    __shared__ _Float16 Pw[4][16 * 40]; // 5 KB
    __shared__ int   lab[32];
    __shared__ float mfv[32];

    const int tid  = threadIdx.x;
    const int lane = tid & 63;
    const int wv   = tid >> 6;
    const int l15  = lane & 15;
    const int quad = lane >> 4;

    // XCD-aware decode: the 16 qt-blocks sharing (b,sp) land on one XCD slot
    const int f   = blockIdx.x;
    const int xcd = f & 7;
    const int seq = f >> 3;
    const int qt  = seq & 15;
    const int u   = seq >> 4;
    const int pr  = u * 8 + xcd;
    const int b   = pr >> nsh;
    const int sp  = pr & ((1 << nsh) - 1);
    const int q0  = qt * 64;

    V16h qfr[8];
    {
        const long qrow = (long)b * WNQ + q0 + wv * 16 + l15;
#pragma unroll
        for (int ks = 0; ks < 8; ++ks)
            qfr[ks].v = *(const int4*)(qf + qrow * 256 + ks * 32 + quad * 8);
    }

    floatx4 O[18];
#pragma unroll
    for (int i = 0; i < 18; ++i) O[i] = (floatx4)(0.0f);
    float m_run = -INFINITY, l_run = 0.f;

    for (int it = 0; it < jtiles; ++it) {
        const int jb = sp * (jtiles * 32) + it * 32;
        __syncthreads();
        {   // ---- async stage both layouts ----
            const long cbase = ((long)b * WNC + jb) * 256;
#pragma unroll
            for (int t = 0; t < 4; ++t) {
                const int idx = wv * 4 + t;            // 0..15
                const int ks = idx >> 1, jh = idx & 1;
                async_lds16(cf + cbase + (jh * 16 + l15) * 256 + ks * 32 + quad * 8,
                            &sA[idx * 512]);
            }
            const long tbase = (long)b * 1048576 + jb;
#pragma unroll
            for (int t = 0; t < 4; ++t) {
                const int W = wv * 4 + t;              // d-block 0..15
                async_lds16(cfT + tbase + (long)(W * 16 + (lane >> 2)) * 4096 + (lane & 3) * 8,
                            &sB[W * 512]);
            }
            if (tid < 32)      lab[tid]      = labels[(long)b * WNC + jb + tid];
            else if (tid < 64) mfv[tid - 32] = maskp[(long)b * WNC + jb + tid - 32];
        }
        __syncthreads();

        // ---- S^T = c (A from sA) . q^T (B regs) ----
        floatx4 accS0 = (floatx4)(0.0f), accS1 = (floatx4)(0.0f);
#pragma unroll
        for (int ks = 0; ks < 8; ++ks) {
            V16h a0, a1;
            a0.v = *(const int4*)&sA[(ks * 2 + 0) * 512 + (quad * 16 + l15) * 8];
            a1.v = *(const int4*)&sA[(ks * 2 + 1) * 512 + (quad * 16 + l15) * 8];
            accS0 = __builtin_amdgcn_mfma_f32_16x16x32_f16(a0.h8, qfr[ks].h8, accS0, 0, 0, 0);
            accS1 = __builtin_amdgcn_mfma_f32_16x16x32_f16(a1.h8, qfr[ks].h8, accS1, 0, 0, 0);
        }
#pragma unroll
        for (int r = 0; r < 4; ++r) {
            accS0[r] *= mfv[quad * 4 + r];
            accS1[r] *= mfv[16 + quad * 4 + r];
        }

        // ---- online softmax per q = lane&15 ----
        float v = fmaxf(fmaxf(fmaxf(accS0[0], accS0[1]), fmaxf(accS0[2], accS0[3])),
                        fmaxf(fmaxf(accS1[0], accS1[1]), fmaxf(accS1[2], accS1[3])));
        v = fmaxf(v, __shfl_xor(v, 16, 64));
        v = fmaxf(v, __shfl_xor(v, 32, 64));
        const float m_new = fmaxf(m_run, v);
        const float alpha = __expf(m_run - m_new);
        float p[8]; float ts = 0.f;
#pragma unroll
        for (int r = 0; r < 4; ++r) {
            p[r]     = __expf(accS0[r] - m_new); ts += p[r];
            p[4 + r] = __expf(accS1[r] - m_new); ts += p[4 + r];
        }
        ts += __shfl_xor(ts, 16, 64);
        ts += __shfl_xor(ts, 32, 64);
        l_run = l_run * alpha + ts;
        m_run = m_new;

        float ar[4];
#pragma unroll
        for (int r = 0; r < 4; ++r) ar[r] = __shfl(alpha, quad * 4 + r, 64);
#pragma unroll
        for (int fo = 0; fo < 18; ++fo)
#pragma unroll
            for (int r = 0; r < 4; ++r) O[fo][r] *= ar[r];

        // ---- P -> per-wave LDS (A layout [q][j]) ----
#pragma unroll
        for (int jf = 0; jf < 2; ++jf) {
            H4 w;
#pragma unroll
            for (int r = 0; r < 4; ++r) w.h[r] = (_Float16)p[jf * 4 + r];
            *(uint2*)&Pw[wv][l15 * 40 + jf * 16 + quad * 4] = w.u;
        }
        asm volatile("" ::: "memory");
        V16h pf;
        pf.v = *(const int4*)&Pw[wv][l15 * 40 + quad * 8];

        // ---- onehot fragments in VGPRs ----
        V16h oh0, oh1;
#pragma unroll
        for (int i = 0; i < 8; ++i) {
            const int lv = lab[quad * 8 + i];
            oh0.h[i] = (lv == l15)        ? (_Float16)1.0f : (_Float16)0.0f;
            oh1.h[i] = (lv == (l15 + 16)) ? (_Float16)1.0f : (_Float16)0.0f;
        }

        // ---- O += P @ [c | onehot] (B from sB) ----
#pragma unroll
        for (int dt = 0; dt < 16; ++dt) {
            V16h bfr;
            bfr.v = *(const int4*)&sB[((dt * 16 + l15) * 4 + quad) * 8];
            O[dt] = __builtin_amdgcn_mfma_f32_16x16x32_f16(pf.h8, bfr.h8, O[dt], 0, 0, 0);
        }
        O[16] = __builtin_amdgcn_mfma_f32_16x16x32_f16(pf.h8, oh0.h8, O[16], 0, 0, 0);
        O[17] = __builtin_amdgcn_mfma_f32_16x16x32_f16(pf.h8, oh1.h8, O[17], 0, 0, 0);
    }

    {   // ---- store fp16 partials + stats ----
        const long orow0 = (long)(sp * WB + b) * WNQ + q0 + wv * 16;
#pragma unroll
        for (int dt = 0; dt < 18; ++dt)
#pragma unroll
            for (int r = 0; r < 4; ++r) {
                H4 h; h.h[0] = (_Float16)O[dt][r];
                Oh[(orow0 + quad * 4 + r) * 288 + dt * 16 + l15] = h.s[0];
            }
        if (lane < 16) {
            const long sidx = (long)(sp * WB + b) * WNQ + q0 + wv * 16 + lane;
            Mst[sidx] = m_run;
            Lst[sidx] = l_run;
        }
    }
}

// ---------------------------------------------------------------------------
// Combine splits + log_softmax(gen) + gate + logaddexp. 4 rows per block.
// ---------------------------------------------------------------------------
__global__ __launch_bounds__(256) void final_kernel(
    const float* __restrict__ genlog,
    const unsigned short* __restrict__ Oh,
    const float* __restrict__ Mst,
    const float* __restrict__ Lst,
    const float* __restrict__ Wcp,
    const float* __restrict__ bcp,
    float* __restrict__ outp,
    int ns)
{
    __shared__ float gA[4][32];
    __shared__ float cdA[4][32];

    const int tid  = threadIdx.x;
    const int lane = tid & 63;
    const int wv   = tid >> 6;
    const int row  = blockIdx.x * 4 + wv;

    float ms[8];
#pragma unroll
    for (int s = 0; s < 8; ++s) ms[s] = (s < ns) ? Mst[(long)s * NROWS + row] : -INFINITY;
    float mstar = -INFINITY;
#pragma unroll
    for (int s = 0; s < 8; ++s) mstar = fmaxf(mstar, ms[s]);
    float wgt[8]; float L = 0.f;
#pragma unroll
    for (int s = 0; s < 8; ++s) {
        wgt[s] = (ms[s] == -INFINITY) ? 0.f : __expf(ms[s] - mstar);
        if (s < ns) L += Lst[(long)s * NROWS + row] * wgt[s];
    }

    const int d0 = lane * 4;
    float ctx[4] = {0.f, 0.f, 0.f, 0.f};
#pragma unroll
    for (int s = 0; s < 8; ++s) {
        if (s < ns) {
            H4 t; t.u = *(const uint2*)&Oh[((long)s * NROWS + row) * 288 + d0];
#pragma unroll
            for (int i = 0; i < 4; ++i) ctx[i] += wgt[s] * (float)t.h[i];
        }
    }

    float cls[4] = {0.f, 0.f, 0.f, 0.f};
    if (lane < 8) {
#pragma unroll
        for (int s = 0; s < 8; ++s) {
            if (s < ns) {
                H4 t; t.u = *(const uint2*)&Oh[((long)s * NROWS + row) * 288 + 256 + lane * 4];
#pragma unroll
                for (int i = 0; i < 4; ++i) cls[i] += wgt[s] * (float)t.h[i];
            }
        }
    }

    float g = (lane < 25) ? genlog[(long)row * 32 + lane] : -INFINITY;
    float mg = g;
#pragma unroll
    for (int off = 32; off >= 1; off >>= 1) mg = fmaxf(mg, __shfl_xor(mg, off, 64));
    float se = (lane < 25) ? __expf(g - mg) : 0.f;
#pragma unroll
    for (int off = 32; off >= 1; off >>= 1) se += __shfl_xor(se, off, 64);
    const float glsm = g - mg - logf(se);

    const float qgate = genlog[(long)row * 32 + 25];
    const float invL = 1.f / L;
    float part = 0.f;
#pragma unroll
    for (int i = 0; i < 4; ++i)
        part += ctx[i] * invL * Wcp[256 + d0 + i];
#pragma unroll
    for (int off = 32; off >= 1; off >>= 1) part += __shfl_xor(part, off, 64);
    const float logit = qgate + part + bcp[0];

    const float lscp  = logsig(logit);
    const float lsgen = logsig(-logit);
    const float logL  = logf(L);

    if (lane < 8) {
#pragma unroll
        for (int i = 0; i < 4; ++i)
            cdA[wv][lane * 4 + i] = (cls[i] > 0.f) ? (logf(cls[i]) - logL) : -INFINITY;
    }
    if (lane < 25) gA[wv][lane] = glsm;
    __syncthreads();

    if (lane < 25) {
        const float a  = lscp + cdA[wv][lane];
        const float bb = lsgen + gA[wv][lane];
        const float mx = fmaxf(a, bb);
        const float o  = (mx == -INFINITY) ? -INFINITY
                         : mx + log1pf(__expf(fminf(a, bb) - mx));
        outp[(long)row * 25 + lane] = o;
    }
}

// ---------------------------------------------------------------------------
extern "C" void kernel_launch(void* const* d_in, const int* in_sizes, int n_in,
                              void* d_out, int out_size, void* d_ws, size_t ws_size,
                              hipStream_t stream) {
    const float* q_head = (const float*)d_in[0];
    const float* q_tail = (const float*)d_in[1];
    const float* c_head = (const float*)d_in[2];
    const float* c_tail = (const float*)d_in[3];
    const int*   labels = (const int*)d_in[4];
    const float* maskp  = (const float*)d_in[5];
    const float* Wrel   = (const float*)d_in[6];
    const float* brel   = (const float*)d_in[7];
    const float* Wgen   = (const float*)d_in[8];
    const float* bgen   = (const float*)d_in[9];
    const float* Wcp    = (const float*)d_in[10];
    const float* bcp    = (const float*)d_in[11];

    // ws layout (base 39,075,840 B + ns*(4,718,592 + 65,536))
    auto need = [](long ns) -> long { return 39075840l + ns * 4784128l; };
    int ns = 8, nsh = 3;
    if ((long)ws_size < need(8)) { ns = 4; nsh = 2; }
    if ((long)ws_size < need(4)) { ns = 2; nsh = 1; }
    if ((long)ws_size < need(2)) { ns = 1; nsh = 0; }
    const int jtiles = 128 / ns;

    char* ws = (char*)d_ws;
    _Float16* Qf     = (_Float16*)(ws);                   //  4 MB
    _Float16* Cf     = (_Float16*)(ws + 4194304l);        // 16 MB
    _Float16* CfT    = (_Float16*)(ws + 20971520l);       // 16 MB
    _Float16* WT     = (_Float16*)(ws + 37748736l);       // 256 KB
    _Float16* GenB   = (_Float16*)(ws + 38010880l);       // 16 KB
    float*    genlog = (float*)   (ws + 38027264l);       //  1 MB
    unsigned short* Oh = (unsigned short*)(ws + 39075840l);  // ns*4.5 MB fp16
    float*    Mst    = (float*)   (ws + 39075840l + (long)ns * 4718592l);
    float*    Lst    = Mst + (long)ns * NROWS;

    hipLaunchKernelGGL(wprep_kernel, dim3(288), dim3(256), 0, stream,
                       Wrel, Wgen, Wcp, WT, GenB);
    hipLaunchKernelGGL(emb_kernel, dim3(640), dim3(256), 0, stream,
                       q_head, q_tail, c_head, c_tail, WT, brel, Qf, Cf, CfT);
    hipLaunchKernelGGL(gen_kernel, dim3(128), dim3(256), 0, stream,
                       Qf, GenB, bgen, genlog);
    hipLaunchKernelGGL(attn_kernel, dim3(16 * 8 * ns), dim3(256), 0, stream,
                       Qf, Cf, CfT, labels, maskp, Oh, Mst, Lst, jtiles, nsh);
    hipLaunchKernelGGL(final_kernel, dim3(NROWS / 4), dim3(256), 0, stream,
                       genlog, Oh, Mst, Lst, Wcp, bcp, (float*)d_out, ns);
}

// Round 6
// 288.218 us; speedup vs baseline: 1.3852x; 1.2553x over previous
//
#include <hip/hip_runtime.h>

// B=8, NQ=1024, NC=4096, D=256, C+1=25. FP32 I/O; labels int32.
// All-fp16 MFMA pipeline. R6: double-buffered async staging in attn (one
// barrier per j-tile, prefetch hidden under compute) + software-pipelined emb.

typedef __attribute__((ext_vector_type(8))) _Float16 half8;
typedef __attribute__((ext_vector_type(4))) float floatx4;

#define WB 8
#define WNQ 1024
#define WNC 4096
#define NROWS 8192          // B*NQ

static __device__ __forceinline__ float logsig(float x) {
    return (x >= 0.f) ? -log1pf(__expf(-x)) : x - log1pf(__expf(x));
}

union V16h { int4 v; half8 h8; _Float16 h[8]; unsigned short s[8]; uint2 u2[2]; };
union F8   { float4 v[2]; float f[8]; };
union H4   { _Float16 h[4]; uint2 u; unsigned short s[4]; };

static __device__ __forceinline__ void async_lds16(const _Float16* g, _Float16* l) {
    __builtin_amdgcn_global_load_lds(
        (const __attribute__((address_space(1))) unsigned int*)g,
        (__attribute__((address_space(3))) unsigned int*)l,
        16, 0, 0);
}

// ---------------------------------------------------------------------------
// wprep: WT fp16 [256 n][512 k] = W_rel^T; GenB fp16 [32 n][256 k].
// ---------------------------------------------------------------------------
__global__ void wprep_kernel(const float* __restrict__ Wrel,
                             const float* __restrict__ Wgen,
                             const float* __restrict__ Wcp,
                             _Float16* __restrict__ WT,
                             _Float16* __restrict__ GenB)
{
    const int bx = blockIdx.x;
    if (bx < 256) {
        const int n = bx;
        for (int k = threadIdx.x; k < 512; k += 256)
            WT[(long)n * 512 + k] = (_Float16)Wrel[(long)k * 256 + n];
    } else {
        const int n = bx - 256;
        const int k = threadIdx.x;
        float v = 0.f;
        if (n < 25)       v = Wgen[(long)k * 25 + n];
        else if (n == 25) v = Wcp[k];
        GenB[(long)n * 256 + k] = (_Float16)v;
    }
}

// ---------------------------------------------------------------------------
// emb: concat(head,tail) @ W_rel + b_rel -> fp16 (+ transposed CfT for c).
// Block = 64m x 256n, 4 waves (wave owns 64 n). Software pipeline:
// A fp32->regs (iter ahead) -> cvt -> dbuf LDS (shared); W->regs iter ahead.
// Blocks 0..127 q, 128..639 c.
// ---------------------------------------------------------------------------
__global__ __launch_bounds__(256, 3) void emb_kernel(
    const float* __restrict__ q_head, const float* __restrict__ q_tail,
    const float* __restrict__ c_head, const float* __restrict__ c_tail,
    const _Float16* __restrict__ WT,
    const float* __restrict__ brel,
    _Float16* __restrict__ Qf, _Float16* __restrict__ Cf,
    _Float16* __restrict__ CfT)
{
    __shared__ _Float16 sA[2][2048];   // [m 64][k 32] fp16, unit u = m*4+kc

    const int tid  = threadIdx.x;
    const int lane = tid & 63;
    const int wv   = tid >> 6;
    const int l15  = lane & 15;
    const int quad = lane >> 4;
    const int n0   = wv * 64;

    const float* head; const float* tail; _Float16* Ef;
    long m0; bool isQ;
    if (blockIdx.x < 128) {
        isQ = true;  head = q_head; tail = q_tail; Ef = Qf;
        m0 = (long)blockIdx.x * 64;
    } else {
        isQ = false; head = c_head; tail = c_tail; Ef = Cf;
        m0 = (long)(blockIdx.x - 128) * 64;
    }

    const long arow = m0 + (tid >> 2);
    const int  akc  = (tid & 3) * 8;

    floatx4 acc[4][4];
#pragma unroll
    for (int a = 0; a < 4; ++a)
#pragma unroll
        for (int bq = 0; bq < 4; ++bq) acc[a][bq] = (floatx4)(0.0f);

    // pipeline preload (ks = 0)
    F8 aCur;
    aCur.v[0] = *(const float4*)(head + arow * 256 + akc);
    aCur.v[1] = *(const float4*)(head + arow * 256 + akc + 4);
    V16h wCur[4];
#pragma unroll
    for (int nt = 0; nt < 4; ++nt)
        wCur[nt].v = *(const int4*)(WT + (long)(n0 + nt * 16 + l15) * 512 + quad * 8);

    for (int ks = 0; ks < 16; ++ks) {
        // cvt + stage current A into buf[ks&1]
        {
            V16h hp;
#pragma unroll
            for (int i = 0; i < 8; ++i) hp.h[i] = (_Float16)aCur.f[i];
            *(int4*)&sA[ks & 1][tid * 8] = hp.v;
        }
        // issue next iteration's loads (hidden under this iter's compute)
        F8 aNxt; V16h wNxt[4];
        if (ks < 15) {
            const int kg = (ks + 1) * 32;
            const float* srcb = (kg < 256) ? (head + kg) : (tail + (kg - 256));
            aNxt.v[0] = *(const float4*)(srcb + arow * 256 + akc);
            aNxt.v[1] = *(const float4*)(srcb + arow * 256 + akc + 4);
#pragma unroll
            for (int nt = 0; nt < 4; ++nt)
                wNxt[nt].v = *(const int4*)(WT + (long)(n0 + nt * 16 + l15) * 512 + kg + quad * 8);
        } else {
            aNxt = aCur;
#pragma unroll
            for (int nt = 0; nt < 4; ++nt) wNxt[nt] = wCur[nt];
        }
        __syncthreads();

        V16h af[4];
#pragma unroll
        for (int mb = 0; mb < 4; ++mb)
            af[mb].v = *(const int4*)&sA[ks & 1][(mb * 16 + l15) * 32 + quad * 8];
#pragma unroll
        for (int mb = 0; mb < 4; ++mb)
#pragma unroll
            for (int nt = 0; nt < 4; ++nt)
                acc[mb][nt] = __builtin_amdgcn_mfma_f32_16x16x32_f16(af[mb].h8, wCur[nt].h8, acc[mb][nt], 0, 0, 0);

        aCur = aNxt;
#pragma unroll
        for (int nt = 0; nt < 4; ++nt) wCur[nt] = wNxt[nt];
    }

    float bias[4];
#pragma unroll
    for (int nt = 0; nt < 4; ++nt) bias[nt] = brel[n0 + nt * 16 + l15];

    const int bidx = (int)(m0 >> 12);
    const int jc0  = (int)(m0 & 4095);
#pragma unroll
    for (int mb = 0; mb < 4; ++mb)
#pragma unroll
        for (int nt = 0; nt < 4; ++nt)
#pragma unroll
            for (int r = 0; r < 4; ++r) {
                const long row = m0 + mb * 16 + quad * 4 + r;
                const _Float16 h = (_Float16)(acc[mb][nt][r] + bias[nt]);
                Ef[row * 256 + n0 + nt * 16 + l15] = h;
                if (!isQ) {
                    const int jc = jc0 + mb * 16 + quad * 4 + r;
                    CfT[(long)bidx * 1048576 + (long)(n0 + nt * 16 + l15) * 4096 + jc] = h;
                }
            }
}

// ---------------------------------------------------------------------------
// gen head: genlog[8192][32] = q_emb @ [Wgen | Wcp_q] (+bgen).
// ---------------------------------------------------------------------------
__global__ __launch_bounds__(256, 4) void gen_kernel(
    const _Float16* __restrict__ Qf,
    const _Float16* __restrict__ GenB,
    const float* __restrict__ bgen,
    float* __restrict__ genlog)
{
    const int tid  = threadIdx.x;
    const int lane = tid & 63;
    const int wv   = tid >> 6;
    const int l15  = lane & 15;
    const int quad = lane >> 4;
    const long m0  = (long)blockIdx.x * 64 + wv * 16;

    floatx4 acc[2];
    acc[0] = (floatx4)(0.0f); acc[1] = (floatx4)(0.0f);
#pragma unroll
    for (int ks = 0; ks < 8; ++ks) {
        V16h a, b0, b1;
        a.v  = *(const int4*)(Qf + (m0 + l15) * 256 + ks * 32 + quad * 8);
        b0.v = *(const int4*)(GenB + (long)(l15)      * 256 + ks * 32 + quad * 8);
        b1.v = *(const int4*)(GenB + (long)(16 + l15) * 256 + ks * 32 + quad * 8);
        acc[0] = __builtin_amdgcn_mfma_f32_16x16x32_f16(a.h8, b0.h8, acc[0], 0, 0, 0);
        acc[1] = __builtin_amdgcn_mfma_f32_16x16x32_f16(a.h8, b1.h8, acc[1], 0, 0, 0);
    }
#pragma unroll
    for (int nt = 0; nt < 2; ++nt) {
        const int col = nt * 16 + l15;
        const float bias = (col < 25) ? bgen[col] : 0.f;
#pragma unroll
        for (int r = 0; r < 4; ++r)
            genlog[(m0 + quad * 4 + r) * 32 + col] = acc[nt][r] + bias;
    }
}

// ---------------------------------------------------------------------------
// Fused flash attention + grouped class sums. grid 16qt*8b*ns (XCD swizzle).
// Double-buffered sA (natural) / sB (transposed) via global_load_lds;
// ONE barrier per iteration, prefetch of tile it+1 hidden under compute(it).
// ---------------------------------------------------------------------------
__global__ __launch_bounds__(256, 2) void attn_kernel(
    const _Float16* __restrict__ qf,
    const _Float16* __restrict__ cf,
    const _Float16* __restrict__ cfT,
    const int*      __restrict__ labels,
    const float*    __restrict__ maskp,
    unsigned short* __restrict__ Oh,    // fp16 [ns*8192][288]
    float* __restrict__ Mst,
    float* __restrict__ Lst,
    int jtiles, int nsh)
{
    __shared__ _Float16 sA[2][8192];    // 2 x 16 KB
    __shared__ _Float16 sB[2][8192];    // 2 x 16 KB
    __shared__ _Float16 Pw[4][16 * 40]; // 5 KB

    const int tid  = threadIdx.x;
    const int lane = tid & 63;
    const int wv   = tid >> 6;
    const int l15  = lane & 15;
    const int quad = lane >> 4;

    const int f   = blockIdx.x;
    const int xcd = f & 7;
    const int seq = f >> 3;
    const int qt  = seq & 15;
    const int u   = seq >> 4;
    const int pr  = u * 8 + xcd;
    const int b   = pr >> nsh;
    const int sp  = pr & ((1 << nsh) - 1);
    const int q0  = qt * 64;

    V16h qfr[8];
    {
        const long qrow = (long)b * WNQ + q0 + wv * 16 + l15;
#pragma unroll
        for (int ks = 0; ks < 8; ++ks)
            qfr[ks].v = *(const int4*)(qf + qrow * 256 + ks * 32 + quad * 8);
    }

    floatx4 O[18];
#pragma unroll
    for (int i = 0; i < 18; ++i) O[i] = (floatx4)(0.0f);
    float m_run = -INFINITY, l_run = 0.f;

    const int jb0 = sp * (jtiles * 32);

    // stage tile jb into buffer bf
    auto stage = [&](int bf, int jb) {
        const long cbase = ((long)b * WNC + jb) * 256;
#pragma unroll
        for (int t = 0; t < 4; ++t) {
            const int idx = wv * 4 + t;            // 0..15
            const int ks = idx >> 1, jh = idx & 1;
            async_lds16(cf + cbase + (jh * 16 + l15) * 256 + ks * 32 + quad * 8,
                        &sA[bf][idx * 512]);
        }
        const long tbase = (long)b * 1048576 + jb;
#pragma unroll
        for (int t = 0; t < 4; ++t) {
            const int W = wv * 4 + t;              // d-block 0..15
            async_lds16(cfT + tbase + (long)(W * 16 + (lane >> 2)) * 4096 + (lane & 3) * 8,
                        &sB[bf][W * 512]);
        }
    };

    stage(0, jb0);

    for (int it = 0; it < jtiles; ++it) {
        const int cur = it & 1;
        const int jb  = jb0 + it * 32;
        __syncthreads();                       // buf[cur] ready (vmcnt drained)
        if (it + 1 < jtiles) stage(cur ^ 1, jb + 32);

        // mask + labels straight from L2 (small, redundant, no LDS)
        const float4 mv0 = *(const float4*)(maskp + (long)b * WNC + jb + quad * 4);
        const float4 mv1 = *(const float4*)(maskp + (long)b * WNC + jb + 16 + quad * 4);
        const int4 lb0 = *(const int4*)(labels + (long)b * WNC + jb + quad * 8);
        const int4 lb1 = *(const int4*)(labels + (long)b * WNC + jb + quad * 8 + 4);

        // ---- S^T = c (A from sA) . q^T (B regs) ----
        floatx4 accS0 = (floatx4)(0.0f), accS1 = (floatx4)(0.0f);
#pragma unroll
        for (int ks = 0; ks < 8; ++ks) {
            V16h a0, a1;
            a0.v = *(const int4*)&sA[cur][(ks * 2 + 0) * 512 + (quad * 16 + l15) * 8];
            a1.v = *(const int4*)&sA[cur][(ks * 2 + 1) * 512 + (quad * 16 + l15) * 8];
            accS0 = __builtin_amdgcn_mfma_f32_16x16x32_f16(a0.h8, qfr[ks].h8, accS0, 0, 0, 0);
            accS1 = __builtin_amdgcn_mfma_f32_16x16x32_f16(a1.h8, qfr[ks].h8, accS1, 0, 0, 0);
        }
        const float* mv0p = (const float*)&mv0;
        const float* mv1p = (const float*)&mv1;
#pragma unroll
        for (int r = 0; r < 4; ++r) {
            accS0[r] *= mv0p[r];
            accS1[r] *= mv1p[r];
        }

        // ---- online softmax per q = lane&15 ----
        float v = fmaxf(fmaxf(fmaxf(accS0[0], accS0[1]), fmaxf(accS0[2], accS0[3])),
                        fmaxf(fmaxf(accS1[0], accS1[1]), fmaxf(accS1[2], accS1[3])));
        v = fmaxf(v, __shfl_xor(v, 16, 64));
        v = fmaxf(v, __shfl_xor(v, 32, 64));
        const float m_new = fmaxf(m_run, v);
        const float alpha = __expf(m_run - m_new);
        float p[8]; float ts = 0.f;
#pragma unroll
        for (int r = 0; r < 4; ++r) {
            p[r]     = __expf(accS0[r] - m_new); ts += p[r];
            p[4 + r] = __expf(accS1[r] - m_new); ts += p[4 + r];
        }
        ts += __shfl_xor(ts, 16, 64);
        ts += __shfl_xor(ts, 32, 64);
        l_run = l_run * alpha + ts;
        m_run = m_new;

        float ar[4];
#pragma unroll
        for (int r = 0; r < 4; ++r) ar[r] = __shfl(alpha, quad * 4 + r, 64);
#pragma unroll
        for (int fo = 0; fo < 18; ++fo)
#pragma unroll
            for (int r = 0; r < 4; ++r) O[fo][r] *= ar[r];

        // ---- P -> per-wave LDS (A layout [q][j]) ----
#pragma unroll
        for (int jf = 0; jf < 2; ++jf) {
            H4 w;
#pragma unroll
            for (int r = 0; r < 4; ++r) w.h[r] = (_Float16)p[jf * 4 + r];
            *(uint2*)&Pw[wv][l15 * 40 + jf * 16 + quad * 4] = w.u;
        }
        asm volatile("" ::: "memory");
        V16h pf;
        pf.v = *(const int4*)&Pw[wv][l15 * 40 + quad * 8];

        // ---- onehot fragments in VGPRs ----
        const int* lbp0 = (const int*)&lb0;
        const int* lbp1 = (const int*)&lb1;
        V16h oh0, oh1;
#pragma unroll
        for (int i = 0; i < 8; ++i) {
            const int lv = (i < 4) ? lbp0[i] : lbp1[i - 4];
            oh0.h[i] = (lv == l15)        ? (_Float16)1.0f : (_Float16)0.0f;
            oh1.h[i] = (lv == (l15 + 16)) ? (_Float16)1.0f : (_Float16)0.0f;
        }

        // ---- O += P @ [c | onehot] (B from sB) ----
#pragma unroll
        for (int dt = 0; dt < 16; ++dt) {
            V16h bfr;
            bfr.v = *(const int4*)&sB[cur][((dt * 16 + l15) * 4 + quad) * 8];
            O[dt] = __builtin_amdgcn_mfma_f32_16x16x32_f16(pf.h8, bfr.h8, O[dt], 0, 0, 0);
        }
        O[16] = __builtin_amdgcn_mfma_f32_16x16x32_f16(pf.h8, oh0.h8, O[16], 0, 0, 0);
        O[17] = __builtin_amdgcn_mfma_f32_16x16x32_f16(pf.h8, oh1.h8, O[17], 0, 0, 0);
    }

    {   // ---- store fp16 partials + stats ----
        const long orow0 = (long)(sp * WB + b) * WNQ + q0 + wv * 16;
#pragma unroll
        for (int dt = 0; dt < 18; ++dt)
#pragma unroll
            for (int r = 0; r < 4; ++r) {
                H4 h; h.h[0] = (_Float16)O[dt][r];
                Oh[(orow0 + quad * 4 + r) * 288 + dt * 16 + l15] = h.s[0];
            }
        if (lane < 16) {
            const long sidx = (long)(sp * WB + b) * WNQ + q0 + wv * 16 + lane;
            Mst[sidx] = m_run;
            Lst[sidx] = l_run;
        }
    }
}

// ---------------------------------------------------------------------------
// Combine splits + log_softmax(gen) + gate + logaddexp. 4 rows per block.
// ---------------------------------------------------------------------------
__global__ __launch_bounds__(256) void final_kernel(
    const float* __restrict__ genlog,
    const unsigned short* __restrict__ Oh,
    const float* __restrict__ Mst,
    const float* __restrict__ Lst,
    const float* __restrict__ Wcp,
    const float* __restrict__ bcp,
    float* __restrict__ outp,
    int ns)
{
    __shared__ float gA[4][32];
    __shared__ float cdA[4][32];

    const int tid  = threadIdx.x;
    const int lane = tid & 63;
    const int wv   = tid >> 6;
    const int row  = blockIdx.x * 4 + wv;

    float ms[8];
#pragma unroll
    for (int s = 0; s < 8; ++s) ms[s] = (s < ns) ? Mst[(long)s * NROWS + row] : -INFINITY;
    float mstar = -INFINITY;
#pragma unroll
    for (int s = 0; s < 8; ++s) mstar = fmaxf(mstar, ms[s]);
    float wgt[8]; float L = 0.f;
#pragma unroll
    for (int s = 0; s < 8; ++s) {
        wgt[s] = (ms[s] == -INFINITY) ? 0.f : __expf(ms[s] - mstar);
        if (s < ns) L += Lst[(long)s * NROWS + row] * wgt[s];
    }

    const int d0 = lane * 4;
    float ctx[4] = {0.f, 0.f, 0.f, 0.f};
#pragma unroll
    for (int s = 0; s < 8; ++s) {
        if (s < ns) {
            H4 t; t.u = *(const uint2*)&Oh[((long)s * NROWS + row) * 288 + d0];
#pragma unroll
            for (int i = 0; i < 4; ++i) ctx[i] += wgt[s] * (float)t.h[i];
        }
    }

    float cls[4] = {0.f, 0.f, 0.f, 0.f};
    if (lane < 8) {
#pragma unroll
        for (int s = 0; s < 8; ++s) {
            if (s < ns) {
                H4 t; t.u = *(const uint2*)&Oh[((long)s * NROWS + row) * 288 + 256 + lane * 4];
#pragma unroll
                for (int i = 0; i < 4; ++i) cls[i] += wgt[s] * (float)t.h[i];
            }
        }
    }

    float g = (lane < 25) ? genlog[(long)row * 32 + lane] : -INFINITY;
    float mg = g;
#pragma unroll
    for (int off = 32; off >= 1; off >>= 1) mg = fmaxf(mg, __shfl_xor(mg, off, 64));
    float se = (lane < 25) ? __expf(g - mg) : 0.f;
#pragma unroll
    for (int off = 32; off >= 1; off >>= 1) se += __shfl_xor(se, off, 64);
    const float glsm = g - mg - logf(se);

    const float qgate = genlog[(long)row * 32 + 25];
    const float invL = 1.f / L;
    float part = 0.f;
#pragma unroll
    for (int i = 0; i < 4; ++i)
        part += ctx[i] * invL * Wcp[256 + d0 + i];
#pragma unroll
    for (int off = 32; off >= 1; off >>= 1) part += __shfl_xor(part, off, 64);
    const float logit = qgate + part + bcp[0];

    const float lscp  = logsig(logit);
    const float lsgen = logsig(-logit);
    const float logL  = logf(L);

    if (lane < 8) {
#pragma unroll
        for (int i = 0; i < 4; ++i)
            cdA[wv][lane * 4 + i] = (cls[i] > 0.f) ? (logf(cls[i]) - logL) : -INFINITY;
    }
    if (lane < 25) gA[wv][lane] = glsm;
    __syncthreads();

    if (lane < 25) {
        const float a  = lscp + cdA[wv][lane];
        const float bb = lsgen + gA[wv][lane];
        const float mx = fmaxf(a, bb);
        const float o  = (mx == -INFINITY) ? -INFINITY
                         : mx + log1pf(__expf(fminf(a, bb) - mx));
        outp[(long)row * 25 + lane] = o;
    }
}

// ---------------------------------------------------------------------------
extern "C" void kernel_launch(void* const* d_in, const int* in_sizes, int n_in,
                              void* d_out, int out_size, void* d_ws, size_t ws_size,
                              hipStream_t stream) {
    const float* q_head = (const float*)d_in[0];
    const float* q_tail = (const float*)d_in[1];
    const float* c_head = (const float*)d_in[2];
    const float* c_tail = (const float*)d_in[3];
    const int*   labels = (const int*)d_in[4];
    const float* maskp  = (const float*)d_in[5];
    const float* Wrel   = (const float*)d_in[6];
    const float* brel   = (const float*)d_in[7];
    const float* Wgen   = (const float*)d_in[8];
    const float* bgen   = (const float*)d_in[9];
    const float* Wcp    = (const float*)d_in[10];
    const float* bcp    = (const float*)d_in[11];

    auto need = [](long ns) -> long { return 39075840l + ns * 4784128l; };
    int ns = 8, nsh = 3;
    if ((long)ws_size < need(8)) { ns = 4; nsh = 2; }
    if ((long)ws_size < need(4)) { ns = 2; nsh = 1; }
    if ((long)ws_size < need(2)) { ns = 1; nsh = 0; }
    const int jtiles = 128 / ns;

    char* ws = (char*)d_ws;
    _Float16* Qf     = (_Float16*)(ws);                   //  4 MB
    _Float16* Cf     = (_Float16*)(ws + 4194304l);        // 16 MB
    _Float16* CfT    = (_Float16*)(ws + 20971520l);       // 16 MB
    _Float16* WT     = (_Float16*)(ws + 37748736l);       // 256 KB
    _Float16* GenB   = (_Float16*)(ws + 38010880l);       // 16 KB
    float*    genlog = (float*)   (ws + 38027264l);       //  1 MB
    unsigned short* Oh = (unsigned short*)(ws + 39075840l);  // ns*4.5 MB fp16
    float*    Mst    = (float*)   (ws + 39075840l + (long)ns * 4718592l);
    float*    Lst    = Mst + (long)ns * NROWS;

    hipLaunchKernelGGL(wprep_kernel, dim3(288), dim3(256), 0, stream,
                       Wrel, Wgen, Wcp, WT, GenB);
    hipLaunchKernelGGL(emb_kernel, dim3(640), dim3(256), 0, stream,
                       q_head, q_tail, c_head, c_tail, WT, brel, Qf, Cf, CfT);
    hipLaunchKernelGGL(gen_kernel, dim3(128), dim3(256), 0, stream,
                       Qf, GenB, bgen, genlog);
    hipLaunchKernelGGL(attn_kernel, dim3(16 * 8 * ns), dim3(256), 0, stream,
                       Qf, Cf, CfT, labels, maskp, Oh, Mst, Lst, jtiles, nsh);
    hipLaunchKernelGGL(final_kernel, dim3(NROWS / 4), dim3(256), 0, stream,
                       genlog, Oh, Mst, Lst, Wcp, bcp, (float*)d_out, ns);
}